// Round 7
// baseline (215.197 us; speedup 1.0000x reference)
//
#include <hip/hip_runtime.h>
#include <cstdint>

#define B_ROWS 32768
#define DIM    256
#define KCODES 1024
#define NSPLIT 2

typedef _Float16 f16x8 __attribute__((ext_vector_type(8)));
typedef float    f32x4 __attribute__((ext_vector_type(4)));

// ws layout:
//   [0, 512K)        cb_hi  (fp16, per-code 512B rows, PLAIN layout — no swizzle)
//   [512K, 1M)       cb_lo  (fp16, scaled x2048, plain)
//   [1M, 1M+4K)      inv_norm (float[1024])
//   [1M+4K, +512K)   cand   (float2[NSPLIT][B_ROWS] = {dot, bitcast(k)})

// ---------------- prep: codebook -> fp16 hi/lo + 1/norm ----------------
__global__ __launch_bounds__(64) void vq_prep(const float* __restrict__ cb,
                                              _Float16* __restrict__ hi,
                                              _Float16* __restrict__ lo,
                                              float* __restrict__ inv_norm) {
  const int k = blockIdx.x;
  const int lane = threadIdx.x;
  float4 c = reinterpret_cast<const float4*>(cb)[k * 64 + lane];
  float nrm = c.x * c.x + c.y * c.y + c.z * c.z + c.w * c.w;
#pragma unroll
  for (int off = 32; off; off >>= 1) nrm += __shfl_xor(nrm, off);
  if (lane == 0) inv_norm[k] = 1.0f / nrm;

  float f[4] = {c.x, c.y, c.z, c.w};
  _Float16 h[4], l[4];
#pragma unroll
  for (int i = 0; i < 4; ++i) {
    h[i] = (_Float16)f[i];
    l[i] = (_Float16)((f[i] - (float)h[i]) * 2048.0f);
  }
  const int byteoff = k * 512 + lane * 8;   // plain row-major fp16
  *reinterpret_cast<uint2*>((char*)hi + byteoff) = *reinterpret_cast<uint2*>(h);
  *reinterpret_cast<uint2*>((char*)lo + byteoff) = *reinterpret_cast<uint2*>(l);
}

#define MFMA16(a, b, acc) __builtin_amdgcn_mfma_f32_16x16x32_f16((a), (b), (acc), 0, 0, 0)

// ---------------- main: LDS-FREE split-fp16 MFMA GEMM + per-split argmax ----------------
// R9: the R6 kernel was LDS-BW-bound: per CU per t, 8 waves x 16 ds_read_b128 = 128KB
// through the 128 B/cyc LDS unit = 1536 cyc vs 466 cyc MFMA (MfmaUtil 33% = ratio).
// B is only 512KB/split (L2-resident; 16KB/t working set ~ L1-sized) -> read B-fragments
// DIRECTLY from global (per-lane base + imm offset c*64, one pointer bump per t).
// No __shared__, no barriers, no staging, no swizzle: waves free-run, 8-wave TLP +
// compiler scheduling hide L1/L2 latency. Numerics identical to R6 (3-chain split-fp16).
__global__ __launch_bounds__(256, 2) void vq_main(const float* __restrict__ emb,
                                                  const _Float16* __restrict__ cbh,
                                                  const _Float16* __restrict__ cbl,
                                                  const float* __restrict__ inv_g,
                                                  float2* __restrict__ cand) {
  const int flat = threadIdx.x;
  const int wave = flat >> 6;
  const int lane = flat & 63;
  const int quad = lane >> 4;
  const int lr   = lane & 15;

  // same-XCD pairing: blocks b and b+8 are the two splits of one rowblk
  const int b = blockIdx.x;
  const int rowblk = ((b >> 4) << 3) | (b & 7);
  const int split  = (b >> 3) & 1;
  const int t0 = split * 32;         // 32 t-iters of 16 codes each = 512 codes
  const int tend = t0 + 32;

  // A fragments: 32 rows/wave (2 subtiles of 16), whole K-depth, hi+lo, in registers.
  f16x8 Ah[2][8], Al[2][8];
  const int row0 = rowblk * 128 + wave * 32;
#pragma unroll
  for (int s = 0; s < 2; ++s) {
    const float* rp = emb + (size_t)(row0 + s * 16 + lr) * DIM;
#pragma unroll
    for (int c = 0; c < 8; ++c) {
      const float* p = rp + c * 32 + quad * 8;
      float4 f0 = *reinterpret_cast<const float4*>(p);
      float4 f1 = *reinterpret_cast<const float4*>(p + 4);
      float f[8] = {f0.x, f0.y, f0.z, f0.w, f1.x, f1.y, f1.z, f1.w};
      f16x8 h, l;
#pragma unroll
      for (int j = 0; j < 8; ++j) {
        _Float16 hv = (_Float16)f[j];
        h[j] = hv;
        l[j] = (_Float16)((f[j] - (float)hv) * 2048.0f);
      }
      Ah[s][c] = h;
      Al[s][c] = l;
    }
  }

  // Per-lane B base: code (t*16+lr) row start + this lane's K-granule (quad*16B).
  // Per c-iter: +c*64B (compile-time imm offset). Per t: +8192B.
  const char* pH = (const char*)cbh + (size_t)t0 * 8192 + lr * 512 + quad * 16;
  const char* pL = (const char*)cbl + (size_t)t0 * 8192 + lr * 512 + quad * 16;
  const float* pI = inv_g + t0 * 16 + lr;

  float bg[2][4], bd[2][4];
  int   bk[2][4];
#pragma unroll
  for (int s = 0; s < 2; ++s)
#pragma unroll
    for (int r = 0; r < 4; ++r) { bg[s][r] = -1.0f; bd[s][r] = 0.0f; bk[s][r] = t0 * 16; }

  for (int t = t0; t < tend; ++t) {
    f16x8 bh[8], bl[8];
#pragma unroll
    for (int c = 0; c < 8; ++c) {
      bh[c] = *reinterpret_cast<const f16x8*>(pH + c * 64);
      bl[c] = *reinterpret_cast<const f16x8*>(pL + c * 64);
    }
    const float inl = *pI;               // issued with the B loads, used after MFMA

    f32x4 aA0  = {0, 0, 0, 0}, aA1  = {0, 0, 0, 0};
    f32x4 aBa0 = {0, 0, 0, 0}, aBa1 = {0, 0, 0, 0};   // Al * Bh
    f32x4 aBb0 = {0, 0, 0, 0}, aBb1 = {0, 0, 0, 0};   // Ah * Bl

    __builtin_amdgcn_s_setprio(1);
#pragma unroll
    for (int c = 0; c < 8; ++c) {
      aA0  = MFMA16(Ah[0][c], bh[c], aA0);
      aA1  = MFMA16(Ah[1][c], bh[c], aA1);
      aBa0 = MFMA16(Al[0][c], bh[c], aBa0);
      aBa1 = MFMA16(Al[1][c], bh[c], aBa1);
      aBb0 = MFMA16(Ah[0][c], bl[c], aBb0);
      aBb1 = MFMA16(Ah[1][c], bl[c], aBb1);
    }
    __builtin_amdgcn_s_setprio(0);

    // ---------------- epilogue: per-code argmax update ----------------
    const int n = t * 16 + lr;           // C/D layout: col = lane&15
#pragma unroll
    for (int r = 0; r < 4; ++r) {
      float d0 = aA0[r] + (aBa0[r] + aBb0[r]) * 4.8828125e-4f;   // 1/2048
      float g0 = d0 * d0 * inl;
      if (g0 > bg[0][r]) { bg[0][r] = g0; bd[0][r] = d0; bk[0][r] = n; }
      float d1 = aA1[r] + (aBa1[r] + aBb1[r]) * 4.8828125e-4f;
      float g1 = d1 * d1 * inl;
      if (g1 > bg[1][r]) { bg[1][r] = g1; bd[1][r] = d1; bk[1][r] = n; }
    }

    pH += 8192; pL += 8192; pI += 16;
  }

  // cross-lane argmax over the 16 cols of each quad (rows = quad*4+reg per C layout)
#pragma unroll
  for (int s = 0; s < 2; ++s) {
#pragma unroll
    for (int r = 0; r < 4; ++r) {
      float g = bg[s][r]; int k = bk[s][r]; float d = bd[s][r];
#pragma unroll
      for (int m = 1; m < 16; m <<= 1) {
        float g2 = __shfl_xor(g, m);
        int   k2 = __shfl_xor(k, m);
        float d2 = __shfl_xor(d, m);
        if (g2 > g || (g2 == g && k2 < k)) { g = g2; k = k2; d = d2; }
      }
      if (lr == 0) {
        const int row = row0 + s * 16 + quad * 4 + r;
        cand[(size_t)split * B_ROWS + row] = make_float2(d, __int_as_float(k));
      }
    }
  }
}

// ---------------- reduce: pick best split candidate, write z + index ----------------
__global__ __launch_bounds__(256) void vq_reduce(const float2* __restrict__ cand,
                                                 const float* __restrict__ inv_g,
                                                 const float* __restrict__ cb,
                                                 float* __restrict__ out) {
  const int wave = threadIdx.x >> 6;
  const int lane = threadIdx.x & 63;
  const int row = blockIdx.x * 4 + wave;

  float best_g = -1.0f, best_d = 0.0f;
  int best_k = 0;
#pragma unroll
  for (int s = 0; s < NSPLIT; ++s) {
    float2 c = cand[(size_t)s * B_ROWS + row];
    int k = __float_as_int(c.y);
    float g = c.x * c.x * inv_g[k];
    if (g > best_g || (g == best_g && k < best_k)) {
      best_g = g; best_d = c.x; best_k = k;
    }
  }
  const float alpha = best_d * inv_g[best_k];
  float4 c4 = reinterpret_cast<const float4*>(cb)[best_k * 64 + lane];
  float4 z = {alpha * c4.x, alpha * c4.y, alpha * c4.z, alpha * c4.w};
  reinterpret_cast<float4*>(out)[(size_t)row * 64 + lane] = z;
  if (lane == 0) out[(size_t)B_ROWS * DIM + row] = (float)best_k;
}

extern "C" void kernel_launch(void* const* d_in, const int* in_sizes, int n_in,
                              void* d_out, int out_size, void* d_ws, size_t ws_size,
                              hipStream_t stream) {
  const float* emb = (const float*)d_in[0];
  const float* cb  = (const float*)d_in[1];
  _Float16* cbh = (_Float16*)d_ws;
  _Float16* cbl = (_Float16*)((char*)d_ws + (512 << 10));
  float*    inv = (float*)((char*)d_ws + (1 << 20));
  float2*   cand = (float2*)((char*)d_ws + (1 << 20) + 4096);

  vq_prep<<<KCODES, 64, 0, stream>>>(cb, cbh, cbl, inv);
  vq_main<<<(B_ROWS / 128) * NSPLIT, 256, 0, stream>>>(emb, cbh, cbl, inv, cand);
  vq_reduce<<<B_ROWS / 4, 256, 0, stream>>>(cand, inv, cb, (float*)d_out);
}

// Round 8
// 162.259 us; speedup vs baseline: 1.3263x; 1.3263x over previous
//
#include <hip/hip_runtime.h>
#include <cstdint>

#define B_ROWS 32768
#define DIM    256
#define KCODES 1024
#define NSPLIT 2

typedef _Float16 f16x8 __attribute__((ext_vector_type(8)));
typedef float    f32x4 __attribute__((ext_vector_type(4)));

// ws layout:
//   [0, 512K)        cb_hi  (fp16, per-code 512B rows, 16B-granule XOR-swizzled)
//   [512K, 1M)       cb_lo  (fp16, scaled x2048, PLAIN layout — lane-read directly)
//   [1M, 1M+4K)      inv_norm (float[1024])
//   [1M+4K, +512K)   cand   (float2[NSPLIT][B_ROWS] = {dot, bitcast(k)})

// ---------------- prep: codebook -> fp16 hi (swizzled) / lo (plain) + 1/norm ----------------
__global__ __launch_bounds__(64) void vq_prep(const float* __restrict__ cb,
                                              _Float16* __restrict__ hi,
                                              _Float16* __restrict__ lo,
                                              float* __restrict__ inv_norm) {
  const int k = blockIdx.x;
  const int lane = threadIdx.x;
  float4 c = reinterpret_cast<const float4*>(cb)[k * 64 + lane];
  float nrm = c.x * c.x + c.y * c.y + c.z * c.z + c.w * c.w;
#pragma unroll
  for (int off = 32; off; off >>= 1) nrm += __shfl_xor(nrm, off);
  if (lane == 0) inv_norm[k] = 1.0f / nrm;

  float f[4] = {c.x, c.y, c.z, c.w};
  _Float16 h[4], l[4];
#pragma unroll
  for (int i = 0; i < 4; ++i) {
    h[i] = (_Float16)f[i];
    l[i] = (_Float16)((f[i] - (float)h[i]) * 2048.0f);
  }
  // hi: granule swizzle phys = g ^ (code & 15) within the code's 512B row (LDS path)
  const int physH = (lane >> 1) ^ (k & 15);
  const int offH = k * 512 + physH * 16 + (lane & 1) * 8;
  *reinterpret_cast<uint2*>((char*)hi + offH) = *reinterpret_cast<uint2*>(h);
  // lo: plain row-major (global-direct lane reads)
  const int offL = k * 512 + lane * 8;
  *reinterpret_cast<uint2*>((char*)lo + offL) = *reinterpret_cast<uint2*>(l);
}

__device__ __forceinline__ void gld16(const void* g, void* l) {
  __builtin_amdgcn_global_load_lds(
      (const __attribute__((address_space(1))) uint32_t*)g,
      (__attribute__((address_space(3))) uint32_t*)l, 16, 0, 0);
}

#define MFMA16(a, b, acc) __builtin_amdgcn_mfma_f32_16x16x32_f16((a), (b), (acc), 0, 0, 0)

// ---------------- main: hybrid split-fp16 MFMA GEMM + per-split argmax ----------------
// R10: rebalance the memory pipes. R6 funneled 16KB/wave/t through LDS (unit ~35% busy,
// phase-critical) while the vector pipe idled. Now: bh stays in LDS (swizzled, 4-deep,
// 2 gld16/t); bl moves to REGISTERS via half-phase-ahead global prefetch (R9's failure
// was zero prefetch -> latency-exposed; here each 4-reg bl group is issued ~600cyc before
// use). LDS reads halve (16->8/wave/t). Counted vmcnt: ph0 waits (6|4) [newest = stage2 +
// cur1_4], ph1 waits (6|4|0) [newest = cur0_next4 (+stage2)]. stage(t+3) issues AFTER
// ph0's s_barrier: all t-1 readers of its slot passed their lgkmcnt(0) before that
// barrier -> WAR-safe with only 2 barriers/t. Cross-wave tile-t gate: every wave's
// (t-1)-ph0 vmcnt drains stage(t), and the (t-1)-ph1 s_barrier precedes any tile-t read.
__global__ __launch_bounds__(256, 2) void vq_main(const float* __restrict__ emb,
                                                  const _Float16* __restrict__ cbh,
                                                  const _Float16* __restrict__ cbl,
                                                  const float* __restrict__ inv_g,
                                                  float2* __restrict__ cand) {
  __shared__ uint4 Btile[4][512];    // 4 x 8KB hi tiles
  __shared__ float inv_s[KCODES];

  const int flat = threadIdx.x;
  const int wave = flat >> 6;
  const int lane = flat & 63;
  const int quad = lane >> 4;
  const int lr   = lane & 15;

  // same-XCD pairing: blocks b and b+8 are the two splits of one rowblk
  const int b = blockIdx.x;
  const int rowblk = ((b >> 4) << 3) | (b & 7);
  const int split  = (b >> 3) & 1;
  const int t0 = split * 32;         // 32 t-iters of 16 codes each = 512 codes
  const int tend = t0 + 32;

  reinterpret_cast<float4*>(inv_s)[flat] = reinterpret_cast<const float4*>(inv_g)[flat];

  // A fragments: 32 rows/wave (2 subtiles of 16), whole K-depth, hi+lo, in registers.
  f16x8 Ah[2][8], Al[2][8];
  const int row0 = rowblk * 128 + wave * 32;
#pragma unroll
  for (int s = 0; s < 2; ++s) {
    const float* rp = emb + (size_t)(row0 + s * 16 + lr) * DIM;
#pragma unroll
    for (int c = 0; c < 8; ++c) {
      const float* p = rp + c * 32 + quad * 8;
      float4 f0 = *reinterpret_cast<const float4*>(p);
      float4 f1 = *reinterpret_cast<const float4*>(p + 4);
      float f[8] = {f0.x, f0.y, f0.z, f0.w, f1.x, f1.y, f1.z, f1.w};
      f16x8 h, l;
#pragma unroll
      for (int j = 0; j < 8; ++j) {
        _Float16 hv = (_Float16)f[j];
        h[j] = hv;
        l[j] = (_Float16)((f[j] - (float)hv) * 2048.0f);
      }
      Ah[s][c] = h;
      Al[s][c] = l;
    }
  }

  // inv_s visible to all waves before any async staging.
  __syncthreads();

  auto stage = [&](int t) {          // hi-only: 2 x gld16 = 8KB per block
    const char* srcH = (const char*)cbh + t * 8192;
    char* dst = (char*)&Btile[t & 3][0];
    const int off = flat * 16;
    gld16(srcH + off,        dst + off);
    gld16(srcH + 4096 + off, dst + 4096 + off);
  };
  auto blload4 = [&](f16x8 (&dst)[4], int t, int c0) {   // bl[c0..c0+3] -> regs
    const char* p = (const char*)cbl + (size_t)t * 8192
                  + (size_t)(lr * 512 + quad * 16 + c0 * 64);
#pragma unroll
    for (int j = 0; j < 4; ++j)
      dst[j] = *reinterpret_cast<const f16x8*>(p + j * 64);
  };

  f16x8 cur0[4], cur1[4];            // bl(t)[0..3] / bl(t)[4..7]
  stage(t0);
  stage(t0 + 1);
  stage(t0 + 2);
  blload4(cur0, t0, 0);
  // outstanding: stage(t0)2 stage(t0+1)2 stage(t0+2)2 cur0_4; need stage(t0) -> allow 8
  asm volatile("s_waitcnt vmcnt(8)" ::: "memory");
  __builtin_amdgcn_s_barrier();

  float bg[2][4], bd[2][4];
  int   bk[2][4];
#pragma unroll
  for (int s = 0; s < 2; ++s)
#pragma unroll
    for (int r = 0; r < 4; ++r) { bg[s][r] = -1.0f; bd[s][r] = 0.0f; bk[s][r] = t0 * 16; }

  for (int t = t0; t < tend; ++t) {
    const int rem = tend - t;
    const char* buf = (const char*)&Btile[t & 3][0];

    f32x4 aA0  = {0, 0, 0, 0}, aA1  = {0, 0, 0, 0};
    f32x4 aBa0 = {0, 0, 0, 0}, aBa1 = {0, 0, 0, 0};   // Al * Bh
    f32x4 aBb0 = {0, 0, 0, 0}, aBb1 = {0, 0, 0, 0};   // Ah * Bl

    // ---------------- phase 0: c = 0..3 ----------------
    {
      f16x8 bh[4];
#pragma unroll
      for (int c = 0; c < 4; ++c) {
        const int g = (((c * 4 + quad) ^ lr) * 16) + lr * 512;  // de-swizzled granule
        bh[c] = *reinterpret_cast<const f16x8*>(buf + g);
      }
      blload4(cur1, t, 4);               // bl(t)[4..7] for phase 1 (~600cyc ahead)
      __builtin_amdgcn_sched_barrier(0);
      __builtin_amdgcn_s_barrier();
      if (rem > 3) stage(t + 3);         // slot (t-1)&3: all its readers are past lgkm
      asm volatile("s_waitcnt lgkmcnt(0)" ::: "memory");
      __builtin_amdgcn_sched_barrier(0);
      if (rem > 3) asm volatile("s_waitcnt vmcnt(6)" ::: "memory");  // keep stage2+cur1_4
      else         asm volatile("s_waitcnt vmcnt(4)" ::: "memory");  // keep cur1_4
      __builtin_amdgcn_sched_barrier(0);
      __builtin_amdgcn_s_setprio(1);
#pragma unroll
      for (int c = 0; c < 4; ++c) {
        aA0  = MFMA16(Ah[0][c], bh[c], aA0);
        aA1  = MFMA16(Ah[1][c], bh[c], aA1);
        aBa0 = MFMA16(Al[0][c], bh[c], aBa0);
        aBa1 = MFMA16(Al[1][c], bh[c], aBa1);
        aBb0 = MFMA16(Ah[0][c], cur0[c], aBb0);
        aBb1 = MFMA16(Ah[1][c], cur0[c], aBb1);
      }
      __builtin_amdgcn_s_setprio(0);
      __builtin_amdgcn_sched_barrier(0);
    }

    // ---------------- phase 1: c = 4..7 ----------------
    {
      f16x8 bh[4];
#pragma unroll
      for (int c = 0; c < 4; ++c) {
        const int g = ((((c + 4) * 4 + quad) ^ lr) * 16) + lr * 512;
        bh[c] = *reinterpret_cast<const f16x8*>(buf + g);
      }
      if (rem >= 2) blload4(cur0, t + 1, 0);   // bl(t+1)[0..3] for next phase 0
      __builtin_amdgcn_sched_barrier(0);
      __builtin_amdgcn_s_barrier();
      asm volatile("s_waitcnt lgkmcnt(0)" ::: "memory");
      __builtin_amdgcn_sched_barrier(0);
      if (rem > 3)       asm volatile("s_waitcnt vmcnt(6)" ::: "memory"); // keep next4+stage2
      else if (rem >= 2) asm volatile("s_waitcnt vmcnt(4)" ::: "memory"); // keep next4
      else               asm volatile("s_waitcnt vmcnt(0)" ::: "memory");
      __builtin_amdgcn_sched_barrier(0);
      __builtin_amdgcn_s_setprio(1);
#pragma unroll
      for (int c = 0; c < 4; ++c) {
        aA0  = MFMA16(Ah[0][c + 4], bh[c], aA0);
        aA1  = MFMA16(Ah[1][c + 4], bh[c], aA1);
        aBa0 = MFMA16(Al[0][c + 4], bh[c], aBa0);
        aBa1 = MFMA16(Al[1][c + 4], bh[c], aBa1);
        aBb0 = MFMA16(Ah[0][c + 4], cur1[c], aBb0);
        aBb1 = MFMA16(Ah[1][c + 4], cur1[c], aBb1);
      }
      __builtin_amdgcn_s_setprio(0);
      __builtin_amdgcn_sched_barrier(0);
    }

    // ---------------- epilogue: per-code argmax update ----------------
    const int n = t * 16 + lr;             // C/D layout: col = lane&15
    const float inl = inv_s[n];
#pragma unroll
    for (int r = 0; r < 4; ++r) {
      float d0 = aA0[r] + (aBa0[r] + aBb0[r]) * 4.8828125e-4f;   // 1/2048
      float g0 = d0 * d0 * inl;
      if (g0 > bg[0][r]) { bg[0][r] = g0; bd[0][r] = d0; bk[0][r] = n; }
      float d1 = aA1[r] + (aBa1[r] + aBb1[r]) * 4.8828125e-4f;
      float g1 = d1 * d1 * inl;
      if (g1 > bg[1][r]) { bg[1][r] = g1; bd[1][r] = d1; bk[1][r] = n; }
    }
  }

  // cross-lane argmax over the 16 cols of each quad (rows = quad*4+reg per C layout)
#pragma unroll
  for (int s = 0; s < 2; ++s) {
#pragma unroll
    for (int r = 0; r < 4; ++r) {
      float g = bg[s][r]; int k = bk[s][r]; float d = bd[s][r];
#pragma unroll
      for (int m = 1; m < 16; m <<= 1) {
        float g2 = __shfl_xor(g, m);
        int   k2 = __shfl_xor(k, m);
        float d2 = __shfl_xor(d, m);
        if (g2 > g || (g2 == g && k2 < k)) { g = g2; k = k2; d = d2; }
      }
      if (lr == 0) {
        const int row = row0 + s * 16 + quad * 4 + r;
        cand[(size_t)split * B_ROWS + row] = make_float2(d, __int_as_float(k));
      }
    }
  }
}

// ---------------- reduce: pick best split candidate, write z + index ----------------
// R10: 2048 blocks x 16 rows (4 waves x 4 rows unrolled) + nontemporal z stores.
__global__ __launch_bounds__(256) void vq_reduce(const float2* __restrict__ cand,
                                                 const float* __restrict__ inv_g,
                                                 const float* __restrict__ cb,
                                                 float* __restrict__ out) {
  const int wave = threadIdx.x >> 6;
  const int lane = threadIdx.x & 63;
  const int base = blockIdx.x * 16;

#pragma unroll
  for (int i = 0; i < 4; ++i) {
    const int row = base + i * 4 + wave;
    float2 ca = cand[row];
    float2 cbv = cand[(size_t)B_ROWS + row];
    int k0 = __float_as_int(ca.y);
    int k1 = __float_as_int(cbv.y);
    float ga = ca.x * ca.x * inv_g[k0];
    float gb = cbv.x * cbv.x * inv_g[k1];
    float d_; int k_;
    if (ga > gb || (ga == gb && k0 < k1)) { d_ = ca.x; k_ = k0; }
    else                                  { d_ = cbv.x; k_ = k1; }
    const float alpha = d_ * inv_g[k_];
    float4 c4 = reinterpret_cast<const float4*>(cb)[k_ * 64 + lane];
    f32x4 z = {alpha * c4.x, alpha * c4.y, alpha * c4.z, alpha * c4.w};
    __builtin_nontemporal_store(z, reinterpret_cast<f32x4*>(out) + (size_t)row * 64 + lane);
    if (lane == 0) out[(size_t)B_ROWS * DIM + row] = (float)k_;
  }
}

extern "C" void kernel_launch(void* const* d_in, const int* in_sizes, int n_in,
                              void* d_out, int out_size, void* d_ws, size_t ws_size,
                              hipStream_t stream) {
  const float* emb = (const float*)d_in[0];
  const float* cb  = (const float*)d_in[1];
  _Float16* cbh = (_Float16*)d_ws;
  _Float16* cbl = (_Float16*)((char*)d_ws + (512 << 10));
  float*    inv = (float*)((char*)d_ws + (1 << 20));
  float2*   cand = (float2*)((char*)d_ws + (1 << 20) + 4096);

  vq_prep<<<KCODES, 64, 0, stream>>>(cb, cbh, cbl, inv);
  vq_main<<<(B_ROWS / 128) * NSPLIT, 256, 0, stream>>>(emb, cbh, cbl, inv, cand);
  vq_reduce<<<B_ROWS / 16, 256, 0, stream>>>(cand, inv, cb, (float*)d_out);
}